// Round 2
// baseline (11155.960 us; speedup 1.0000x reference)
//
#include <hip/hip_runtime.h>
#include <stdint.h>

typedef unsigned short u16;
typedef unsigned int   u32;
typedef unsigned long long u64;
typedef __bf16 bf16_t;
typedef bf16_t bf16x8 __attribute__((ext_vector_type(8)));
typedef float  f32x4  __attribute__((ext_vector_type(4)));

#define NSTEPS 512

// ---- LDS layout (u16 elements). Strides padded +8 elems: 656B/1040B rows are
// 16B-aligned; row-to-row bank shift of 4 keeps aliasing <=4-way.
#define SW0_STRIDE 328
#define SW1_STRIDE 520
#define SA_STRIDE  328
#define SW0_OFF 0
#define SW1_OFF (64*SW0_STRIDE)             /* 20992 */
#define SA_OFF  (SW1_OFF + 64*SW1_STRIDE)   /* 54272 */
#define SH_OFF  (SA_OFF + 64*SA_STRIDE)     /* 75264 */
#define SMEM_U16 (SH_OFF + 64*16)           /* 76288 */
#define SMEM_BYTES (SMEM_U16*2)             /* 152576 < 160K */

// ---- workspace layout (bytes)
#define WS_RING1 0
#define WS_RING2 262144
#define WS_FLAG1 524288
#define WS_FLAG2 525312
#define WS_TOTAL 526336

__device__ __forceinline__ u16 f2bf(float f) {
  u32 u = __float_as_uint(f);
  u32 r = (u + 0x7fffu + ((u >> 16) & 1u)) >> 16;   // RNE
  return (u16)r;
}
__device__ __forceinline__ float bf2f(u16 b) {
  return __uint_as_float(((u32)b) << 16);
}
__device__ __forceinline__ float sigf(float x) { return 1.f / (1.f + __expf(-x)); }
__device__ __forceinline__ float tanhf_(float x) {
  float e = __expf(-2.f * fabsf(x));
  float t = (1.f - e) / (1.f + e);
  return x >= 0.f ? t : -t;
}

// wave0-only spin: lane (lane&15) watches the 16 flags of its batch group
// (agent scope atomics -> LLC-coherent, no stale cross-XCD reads).
__device__ __forceinline__ void spinwait(int* f, int lane15, int target) {
  if (target <= 0) return;
  int v = __hip_atomic_load(&f[lane15], __ATOMIC_RELAXED, __HIP_MEMORY_SCOPE_AGENT);
  while (__any(v < target)) {
    __builtin_amdgcn_s_sleep(2);
    v = __hip_atomic_load(&f[lane15], __ATOMIC_RELAXED, __HIP_MEMORY_SCOPE_AGENT);
  }
}

__global__ void ws_init_kernel(u32* p, int n) {
  int i = blockIdx.x * blockDim.x + threadIdx.x;
  if (i < n) p[i] = 0u;
}

// Persistent fused 2-layer LSTM.
// grid = 64 blocks: bi = blk>>4 (4 batch groups x 64 rows), j = blk&15
// (16 slices x 16 h-cols; local weight row lr: gate = lr>>4, col = j*16+(lr&15)).
// Wave wv = M-tile (16 rows). MFMA 16x16x32_bf16; C/D: col=lane&15 (h-col),
// row=(lane>>4)*4+reg. acc[nt] = gate nt -> pointwise LSTM update needs no
// cross-lane traffic; c-state stays in VGPRs for all 512 steps.
__global__ void __launch_bounds__(256)
lstm_persistent(const float* __restrict__ x,
                const float* __restrict__ Wih0, const float* __restrict__ Whh0,
                const float* __restrict__ bih0, const float* __restrict__ bhh0,
                const float* __restrict__ Wih1, const float* __restrict__ Whh1,
                const float* __restrict__ bih1, const float* __restrict__ bhh1,
                const float* __restrict__ W1, const float* __restrict__ b1,
                const float* __restrict__ W2, const float* __restrict__ b2,
                float* __restrict__ out, char* __restrict__ ws)
{
  extern __shared__ u16 smem[];
  const int tid  = threadIdx.x;
  const int lane = tid & 63;
  const int l15  = lane & 15;
  const int wv   = tid >> 6;
  const int n16  = lane & 15;
  const int quad = lane >> 4;
  const int blk  = blockIdx.x;
  const int bi   = blk >> 4;     // batch group (4 groups x 64 rows)
  const int j    = blk & 15;     // h-column slice (16 slices x 16 cols)

  bf16_t* ring1 = (bf16_t*)(ws + WS_RING1);   // [2][256][256]
  bf16_t* ring2 = (bf16_t*)(ws + WS_RING2);
  int* flag1 = (int*)(ws + WS_FLAG1);         // [64] steps published (layer0)
  int* flag2 = (int*)(ws + WS_FLAG2);         // [64] steps published (layer1)
  int* f1g = flag1 + bi*16;
  int* f2g = flag2 + bi*16;

  // ---- one-time: stage weight slices fp32->bf16 into LDS ----
  for (int i = 0; i < 20; ++i) {
    int u = tid + i*256;               // 64 rows x 80 float4
    int lr = u / 80, c4 = u % 80;
    int wrow = (lr >> 4)*256 + j*16 + (lr & 15);    // gate*256 + hcol, <=1023
    float4 v = (c4 < 16) ? *(const float4*)(Wih0 + (size_t)wrow*64 + c4*4)
                         : *(const float4*)(Whh0 + (size_t)wrow*256 + (c4-16)*4);
    u16* d = smem + SW0_OFF + lr*SW0_STRIDE + c4*4;
    d[0]=f2bf(v.x); d[1]=f2bf(v.y); d[2]=f2bf(v.z); d[3]=f2bf(v.w);
  }
  for (int i = 0; i < 32; ++i) {
    int u = tid + i*256;               // 64 rows x 128 float4
    int lr = u >> 7, c4 = u & 127;
    int wrow = (lr >> 4)*256 + j*16 + (lr & 15);
    float4 v = (c4 < 64) ? *(const float4*)(Wih1 + (size_t)wrow*256 + c4*4)
                         : *(const float4*)(Whh1 + (size_t)wrow*256 + (c4-64)*4);
    u16* d = smem + SW1_OFF + lr*SW1_STRIDE + c4*4;
    d[0]=f2bf(v.x); d[1]=f2bf(v.y); d[2]=f2bf(v.z); d[3]=f2bf(v.w);
  }
  float b0g[4], b1g[4];
  #pragma unroll
  for (int nt = 0; nt < 4; ++nt) {
    int wrow = nt*256 + j*16 + n16;
    b0g[nt] = bih0[wrow] + bhh0[wrow];
    b1g[nt] = bih1[wrow] + bhh1[wrow];
  }

  const int rowg0 = bi * 64;
  const u16* aP  = smem + SA_OFF  + (wv*16 + n16)*SA_STRIDE  + quad*8;
  const u16* b0P = smem + SW0_OFF + n16*SW0_STRIDE + quad*8;
  const u16* b1P = smem + SW1_OFF + n16*SW1_STRIDE + quad*8;

  float c1r[4] = {0.f,0.f,0.f,0.f};
  float c2r[4] = {0.f,0.f,0.f,0.f};

  for (int t = 0; t < NSTEPS; ++t) {
    // ================= layer 0 =================
    // stage x_t -> sA[:,0:64] (no dependence on flags)
    #pragma unroll
    for (int i = 0; i < 4; ++i) {
      int u = tid + i*256;
      int row = u >> 4, f4 = u & 15;
      float4 v = *(const float4*)(x + ((size_t)(rowg0+row)*NSTEPS + t)*64 + f4*4);
      u16* d = smem + SA_OFF + row*SA_STRIDE + f4*4;
      d[0]=f2bf(v.x); d[1]=f2bf(v.y); d[2]=f2bf(v.z); d[3]=f2bf(v.w);
    }
    if (wv == 0) {
      spinwait(f1g, l15, t);       // read h1_{t-1}
      spinwait(f2g, l15, t-1);     // anti-dep: overwrite h1_{t-2} slot
      __builtin_amdgcn_fence(__ATOMIC_ACQUIRE, "agent");
    }
    __syncthreads();
    { // stage h1_{t-1} -> sA[:,64:320]
      const bf16_t* src = ring1 + (size_t)((t+1)&1)*65536 + (size_t)rowg0*256;
      #pragma unroll
      for (int i = 0; i < 16; ++i) {
        int u = tid + i*256;
        int row = u >> 6, c8 = u & 63;
        u64 v = __hip_atomic_load((const u64*)(src + row*256 + c8*4),
                                  __ATOMIC_RELAXED, __HIP_MEMORY_SCOPE_AGENT);
        *(u64*)(smem + SA_OFF + row*SA_STRIDE + 64 + c8*4) = v;
      }
    }
    __syncthreads();
    {
      f32x4 acc[4] = {{0,0,0,0},{0,0,0,0},{0,0,0,0},{0,0,0,0}};
      for (int kc = 0; kc < 10; ++kc) {       // K = 64(x) + 256(h)
        bf16x8 a = *(const bf16x8*)(aP + kc*32);
        #pragma unroll
        for (int nt = 0; nt < 4; ++nt) {
          bf16x8 bb = *(const bf16x8*)(b0P + nt*16*SW0_STRIDE + kc*32);
          acc[nt] = __builtin_amdgcn_mfma_f32_16x16x32_bf16(a, bb, acc[nt], 0, 0, 0);
        }
      }
      #pragma unroll
      for (int r = 0; r < 4; ++r) {
        float gi = acc[0][r] + b0g[0];
        float gf = acc[1][r] + b0g[1];
        float gg = acc[2][r] + b0g[2];
        float go = acc[3][r] + b0g[3];
        float c  = sigf(gf)*c1r[r] + sigf(gi)*tanhf_(gg);
        c1r[r] = c;
        float h  = sigf(go)*tanhf_(c);
        smem[SH_OFF + (wv*16 + quad*4 + r)*16 + n16] = f2bf(h);
      }
    }
    __syncthreads();
    { // publish h1_t slice (64 rows x 16 cols) -> ring1 (agent scope -> LLC)
      int row = tid >> 2, c4 = tid & 3;
      u64 v = *(const u64*)(smem + SH_OFF + row*16 + c4*4);
      __hip_atomic_store((u64*)(ring1 + (size_t)(t&1)*65536 +
                                (size_t)(rowg0+row)*256 + j*16 + c4*4),
                         v, __ATOMIC_RELAXED, __HIP_MEMORY_SCOPE_AGENT);
    }
    __builtin_amdgcn_fence(__ATOMIC_RELEASE, "agent");
    __syncthreads();
    if (tid == 0)
      __hip_atomic_store(&flag1[blk], t+1, __ATOMIC_RELEASE, __HIP_MEMORY_SCOPE_AGENT);

    // ================= layer 1, pass A: h1_t @ Wih1^T =================
    if (wv == 0) {
      spinwait(f1g, l15, t+1);
      __builtin_amdgcn_fence(__ATOMIC_ACQUIRE, "agent");
    }
    __syncthreads();
    {
      const bf16_t* src = ring1 + (size_t)(t&1)*65536 + (size_t)rowg0*256;
      #pragma unroll
      for (int i = 0; i < 16; ++i) {
        int u = tid + i*256;
        int row = u >> 6, c8 = u & 63;
        u64 v = __hip_atomic_load((const u64*)(src + row*256 + c8*4),
                                  __ATOMIC_RELAXED, __HIP_MEMORY_SCOPE_AGENT);
        *(u64*)(smem + SA_OFF + row*SA_STRIDE + c8*4) = v;
      }
    }
    __syncthreads();
    f32x4 acc2[4] = {{0,0,0,0},{0,0,0,0},{0,0,0,0},{0,0,0,0}};
    for (int kc = 0; kc < 8; ++kc) {
      bf16x8 a = *(const bf16x8*)(aP + kc*32);
      #pragma unroll
      for (int nt = 0; nt < 4; ++nt) {
        bf16x8 bb = *(const bf16x8*)(b1P + nt*16*SW1_STRIDE + kc*32);
        acc2[nt] = __builtin_amdgcn_mfma_f32_16x16x32_bf16(a, bb, acc2[nt], 0, 0, 0);
      }
    }
    // ---- pass B: h2_{t-1} @ Whh1^T ----
    if (wv == 0) {
      spinwait(f2g, l15, t);
      __builtin_amdgcn_fence(__ATOMIC_ACQUIRE, "agent");
    }
    __syncthreads();           // all waves done reading sA(passA)
    {
      const bf16_t* src = ring2 + (size_t)((t+1)&1)*65536 + (size_t)rowg0*256;
      #pragma unroll
      for (int i = 0; i < 16; ++i) {
        int u = tid + i*256;
        int row = u >> 6, c8 = u & 63;
        u64 v = __hip_atomic_load((const u64*)(src + row*256 + c8*4),
                                  __ATOMIC_RELAXED, __HIP_MEMORY_SCOPE_AGENT);
        *(u64*)(smem + SA_OFF + row*SA_STRIDE + c8*4) = v;
      }
    }
    __syncthreads();
    for (int kc = 0; kc < 8; ++kc) {
      bf16x8 a = *(const bf16x8*)(aP + kc*32);
      #pragma unroll
      for (int nt = 0; nt < 4; ++nt) {
        bf16x8 bb = *(const bf16x8*)(b1P + nt*16*SW1_STRIDE + 256 + kc*32);
        acc2[nt] = __builtin_amdgcn_mfma_f32_16x16x32_bf16(a, bb, acc2[nt], 0, 0, 0);
      }
    }
    #pragma unroll
    for (int r = 0; r < 4; ++r) {
      float gi = acc2[0][r] + b1g[0];
      float gf = acc2[1][r] + b1g[1];
      float gg = acc2[2][r] + b1g[2];
      float go = acc2[3][r] + b1g[3];
      float c  = sigf(gf)*c2r[r] + sigf(gi)*tanhf_(gg);
      c2r[r] = c;
      float h  = sigf(go)*tanhf_(c);
      smem[SH_OFF + (wv*16 + quad*4 + r)*16 + n16] = f2bf(h);
    }
    __syncthreads();
    {
      int row = tid >> 2, c4 = tid & 3;
      u64 v = *(const u64*)(smem + SH_OFF + row*16 + c4*4);
      __hip_atomic_store((u64*)(ring2 + (size_t)(t&1)*65536 +
                                (size_t)(rowg0+row)*256 + j*16 + c4*4),
                         v, __ATOMIC_RELAXED, __HIP_MEMORY_SCOPE_AGENT);
    }
    __builtin_amdgcn_fence(__ATOMIC_RELEASE, "agent");
    __syncthreads();
    if (tid == 0)
      __hip_atomic_store(&flag2[blk], t+1, __ATOMIC_RELEASE, __HIP_MEMORY_SCOPE_AGENT);
  }

  // ================= epilogue: y = (last @ W1^T + b1) @ W2^T + b2 =================
  // all 64 blocks participate; block handles batch rows blk*4..blk*4+3
  {
    const int grp = blk >> 4;          // batch group of rows blk*4..blk*4+3
    if (wv == 0) {
      spinwait(flag2 + grp*16, l15, NSTEPS);
      __builtin_amdgcn_fence(__ATOMIC_ACQUIRE, "agent");
    }
    __syncthreads();
    float* lastsh = (float*)smem;      // 4x256
    float* y1sh   = lastsh + 1024;     // 4x1280
    float* psum   = y1sh + 5120;       // 64
    {
      int row = tid >> 6, c8 = tid & 63;
      const bf16_t* src = ring2 + 65536 /*slot 511&1*/ + (size_t)(blk*4 + row)*256 + c8*4;
      u64 v = __hip_atomic_load((const u64*)src, __ATOMIC_RELAXED, __HIP_MEMORY_SCOPE_AGENT);
      lastsh[row*256 + c8*4 + 0] = bf2f((u16)( v        & 0xffffu));
      lastsh[row*256 + c8*4 + 1] = bf2f((u16)((v >> 16) & 0xffffu));
      lastsh[row*256 + c8*4 + 2] = bf2f((u16)((v >> 32) & 0xffffu));
      lastsh[row*256 + c8*4 + 3] = bf2f((u16)((v >> 48) & 0xffffu));
    }
    __syncthreads();
    for (int i = 0; i < 5; ++i) {
      int m = tid + i*256;
      const float* wr = W1 + (size_t)m*256;
      float a0=0.f,a1=0.f,a2=0.f,a3=0.f;
      for (int k = 0; k < 256; ++k) {
        float w = wr[k];
        a0 += w*lastsh[k]; a1 += w*lastsh[256+k];
        a2 += w*lastsh[512+k]; a3 += w*lastsh[768+k];
      }
      float bb = b1[m];
      y1sh[m] = a0+bb; y1sh[1280+m] = a1+bb; y1sh[2560+m] = a2+bb; y1sh[3840+m] = a3+bb;
    }
    __syncthreads();
    if (tid < 64) {
      int row = tid >> 4, o = (tid >> 2) & 3, q = tid & 3;
      const float* w2r = W2 + (size_t)o*1280 + q*320;
      const float* yr  = y1sh + row*1280 + q*320;
      float s = 0.f;
      for (int m = 0; m < 320; ++m) s += w2r[m]*yr[m];
      psum[tid] = s;
    }
    __syncthreads();
    if (tid < 16) {
      int row = tid >> 2, o = tid & 3;
      out[(blk*4 + row)*4 + o] = b2[o] + psum[tid*4+0] + psum[tid*4+1]
                                       + psum[tid*4+2] + psum[tid*4+3];
    }
  }
}

extern "C" void kernel_launch(void* const* d_in, const int* in_sizes, int n_in,
                              void* d_out, int out_size, void* d_ws, size_t ws_size,
                              hipStream_t stream) {
  (void)in_sizes; (void)n_in; (void)out_size; (void)ws_size;
  const float* x    = (const float*)d_in[0];
  const float* Wih0 = (const float*)d_in[1];
  const float* Whh0 = (const float*)d_in[2];
  const float* bih0 = (const float*)d_in[3];
  const float* bhh0 = (const float*)d_in[4];
  const float* Wih1 = (const float*)d_in[5];
  const float* Whh1 = (const float*)d_in[6];
  const float* bih1 = (const float*)d_in[7];
  const float* bhh1 = (const float*)d_in[8];
  const float* W1   = (const float*)d_in[9];
  const float* b1   = (const float*)d_in[10];
  const float* W2   = (const float*)d_in[11];
  const float* b2   = (const float*)d_in[12];
  float* out = (float*)d_out;
  char* ws   = (char*)d_ws;

  // flags + h rings must be zeroed every call (ws is re-poisoned to 0xAA)
  hipLaunchKernelGGL(ws_init_kernel, dim3((WS_TOTAL/4 + 255)/256), dim3(256), 0, stream,
                     (u32*)ws, WS_TOTAL/4);

  hipFuncSetAttribute((const void*)lstm_persistent,
                      hipFuncAttributeMaxDynamicSharedMemorySize, SMEM_BYTES);

  void* args[] = { (void*)&x, (void*)&Wih0, (void*)&Whh0, (void*)&bih0, (void*)&bhh0,
                   (void*)&Wih1, (void*)&Whh1, (void*)&bih1, (void*)&bhh1,
                   (void*)&W1, (void*)&b1, (void*)&W2, (void*)&b2,
                   (void*)&out, (void*)&ws };
  // cooperative launch: guarantees all 64 blocks (1/CU, LDS-bound) co-resident
  hipLaunchCooperativeKernel((const void*)lstm_persistent, dim3(64), dim3(256),
                             args, SMEM_BYTES, stream);
}

// Round 3
// 4697.803 us; speedup vs baseline: 2.3747x; 2.3747x over previous
//
#include <hip/hip_runtime.h>
#include <stdint.h>

typedef unsigned short u16;
typedef unsigned int   u32;
typedef unsigned long long u64;
typedef __bf16 bf16_t;
typedef bf16_t bf16x8 __attribute__((ext_vector_type(8)));
typedef float  f32x4  __attribute__((ext_vector_type(4)));

#define NSTEPS 512
#define RING_D 4                    /* ring depth (slots), power of 2 */
#define SLOT_ELEMS 65536            /* 256 rows x 256 cols bf16 */

// ---- LDS layouts (u16 elements) ----
// L0 blocks: SW0 (64 x 328) + SA0 (64 x 328)      = 84 KB
// L1 blocks: SW1 (64 x 520) + SA1 (64 x 520)      = 133 KB
#define SW0_STRIDE 328
#define SA0_OFF    (64*SW0_STRIDE)
#define SA0_STRIDE 328
#define SW1_STRIDE 520
#define SA1_OFF    (64*SW1_STRIDE)
#define SA1_STRIDE 520
#define SMEM_BYTES (2*(SA1_OFF + 64*SA1_STRIDE))   /* 133120 */

// ---- workspace layout (bytes) ----
#define WS_RING1 0                                  /* RING_D slots */
#define WS_RING2 (RING_D*SLOT_ELEMS*2)              /* 524288 */
#define WS_FLAG1 (2*RING_D*SLOT_ELEMS*2)            /* 1048576 */
#define WS_FLAG2 (WS_FLAG1 + 512)
#define WS_TOTAL (WS_FLAG2 + 512)

__device__ __forceinline__ u16 f2bf(float f) {
  u32 u = __float_as_uint(f);
  u32 r = (u + 0x7fffu + ((u >> 16) & 1u)) >> 16;   // RNE
  return (u16)r;
}
__device__ __forceinline__ float bf2f(u16 b) {
  return __uint_as_float(((u32)b) << 16);
}
__device__ __forceinline__ float sigf(float x) { return 1.f / (1.f + __expf(-x)); }
__device__ __forceinline__ float tanhf_(float x) {
  float e = __expf(-2.f * fabsf(x));
  float t = (1.f - e) / (1.f + e);
  return x >= 0.f ? t : -t;
}

// wave0-only spin: lane (lane&15) watches the 16 flags of a group.
// Agent-scope atomic loads read the LLC directly (coherence point), so no
// fence/L2-invalidate is needed; consumer data loads are control-dependent
// on the flag value and issue only after it resolves.
__device__ __forceinline__ void spinwait(int* f, int lane15, int target) {
  if (target <= 0) return;
  int v = __hip_atomic_load(&f[lane15], __ATOMIC_RELAXED, __HIP_MEMORY_SCOPE_AGENT);
  while (__any(v < target)) {
    __builtin_amdgcn_s_sleep(1);
    v = __hip_atomic_load(&f[lane15], __ATOMIC_RELAXED, __HIP_MEMORY_SCOPE_AGENT);
  }
}

__global__ void ws_init_kernel(u32* p, int n) {
  int i = blockIdx.x * blockDim.x + threadIdx.x;
  if (i < n) p[i] = 0u;
}

// Persistent pipelined 2-layer LSTM.
// 128 blocks: blk<64 -> layer0 worker, blk>=64 -> layer1 worker.
// Within a layer: bi = b>>4 (4 batch groups x 64 rows), j = b&15 (16 col
// slices x 16 h-cols). Wave wv = M-tile (16 rows). MFMA 16x16x32_bf16,
// C/D col=lane&15 (h-col), row=(lane>>4)*4+reg; acc[nt] = gate nt, so the
// pointwise LSTM update is lane-local; c-state lives in VGPRs all 512 steps.
// h handoff: depth-4 rings in LLC via agent atomics; monotone flags.
// Sync per step per block: ONE spin + 3 barriers (no fences).
__global__ void __launch_bounds__(256)
lstm_persistent(const float* __restrict__ x,
                const float* __restrict__ Wih0, const float* __restrict__ Whh0,
                const float* __restrict__ bih0, const float* __restrict__ bhh0,
                const float* __restrict__ Wih1, const float* __restrict__ Whh1,
                const float* __restrict__ bih1, const float* __restrict__ bhh1,
                const float* __restrict__ W1, const float* __restrict__ b1,
                const float* __restrict__ W2, const float* __restrict__ b2,
                float* __restrict__ out, char* __restrict__ ws)
{
  extern __shared__ u16 smem[];
  const int tid  = threadIdx.x;
  const int lane = tid & 63;
  const int l15  = lane & 15;
  const int wv   = tid >> 6;
  const int n16  = lane & 15;
  const int quad = lane >> 4;
  const int blk  = blockIdx.x;

  bf16_t* ring1 = (bf16_t*)(ws + WS_RING1);   // [RING_D][256][256]
  bf16_t* ring2 = (bf16_t*)(ws + WS_RING2);
  int* flag1 = (int*)(ws + WS_FLAG1);         // [64] layer0 steps published
  int* flag2 = (int*)(ws + WS_FLAG2);         // [64] layer1 steps published

  if (blk < 64) {
    // ======================= LAYER-0 WORKER =======================
    const int b  = blk;
    const int bi = b >> 4, j = b & 15;
    const int rowg0 = bi * 64;
    int* f1g = flag1 + bi*16;
    int* f2g = flag2 + bi*16;

    // stage W0 slice fp32->bf16 into LDS (rows: gate*16.. 64 local rows)
    for (int i = 0; i < 20; ++i) {
      int u = tid + i*256;               // 64 rows x 80 float4
      int lr = u / 80, c4 = u % 80;
      int wrow = (lr >> 4)*256 + j*16 + (lr & 15);
      float4 v = (c4 < 16) ? *(const float4*)(Wih0 + (size_t)wrow*64 + c4*4)
                           : *(const float4*)(Whh0 + (size_t)wrow*256 + (c4-16)*4);
      u16* d = smem + lr*SW0_STRIDE + c4*4;
      d[0]=f2bf(v.x); d[1]=f2bf(v.y); d[2]=f2bf(v.z); d[3]=f2bf(v.w);
    }
    float b0g[4];
    #pragma unroll
    for (int nt = 0; nt < 4; ++nt) {
      int wrow = nt*256 + j*16 + n16;
      b0g[nt] = bih0[wrow] + bhh0[wrow];
    }
    const u16* aP = smem + SA0_OFF + (wv*16 + n16)*SA0_STRIDE + quad*8;
    const u16* bP = smem + (n16)*SW0_STRIDE + quad*8;
    float c1r[4] = {0.f,0.f,0.f,0.f};

    for (int t = 0; t < NSTEPS; ++t) {
      // stage x_t -> sA[:,0:64]  (issued before the spin: off critical path)
      #pragma unroll
      for (int i = 0; i < 4; ++i) {
        int u = tid + i*256;
        int row = u >> 4, f4 = u & 15;
        float4 v = *(const float4*)(x + ((size_t)(rowg0+row)*NSTEPS + t)*64 + f4*4);
        u64 pk = (u64)f2bf(v.x) | ((u64)f2bf(v.y)<<16)
               | ((u64)f2bf(v.z)<<32) | ((u64)f2bf(v.w)<<48);
        *(u64*)(smem + SA0_OFF + row*SA0_STRIDE + f4*4) = pk;
      }
      if (wv == 0) {
        spinwait(f1g, l15, t);           // h1_{t-1} published by whole group
        spinwait(f2g, l15, t-(RING_D-1));// L1 done reading h1_{t-RING_D}
      }
      __syncthreads();
      { // stage h1_{t-1} -> sA[:,64:320]
        const bf16_t* src = ring1 + (size_t)((t+RING_D-1)&(RING_D-1))*SLOT_ELEMS
                          + (size_t)rowg0*256;
        #pragma unroll
        for (int i = 0; i < 16; ++i) {
          int u = tid + i*256;
          int row = u >> 6, c8 = u & 63;
          u64 v = __hip_atomic_load((const u64*)(src + row*256 + c8*4),
                                    __ATOMIC_RELAXED, __HIP_MEMORY_SCOPE_AGENT);
          *(u64*)(smem + SA0_OFF + row*SA0_STRIDE + 64 + c8*4) = v;
        }
      }
      __syncthreads();
      f32x4 acc[4] = {{0,0,0,0},{0,0,0,0},{0,0,0,0},{0,0,0,0}};
      for (int kc = 0; kc < 10; ++kc) {          // K = 64(x) + 256(h1)
        bf16x8 a = *(const bf16x8*)(aP + kc*32);
        #pragma unroll
        for (int nt = 0; nt < 4; ++nt) {
          bf16x8 bb = *(const bf16x8*)(bP + nt*16*SW0_STRIDE + kc*32);
          acc[nt] = __builtin_amdgcn_mfma_f32_16x16x32_bf16(a, bb, acc[nt], 0, 0, 0);
        }
      }
      { // pointwise + direct publish from registers (no LDS round-trip)
        bf16_t* dst = ring1 + (size_t)(t&(RING_D-1))*SLOT_ELEMS;
        #pragma unroll
        for (int r = 0; r < 4; ++r) {
          float gi = acc[0][r] + b0g[0];
          float gf = acc[1][r] + b0g[1];
          float gg = acc[2][r] + b0g[2];
          float go = acc[3][r] + b0g[3];
          float c  = sigf(gf)*c1r[r] + sigf(gi)*tanhf_(gg);
          c1r[r] = c;
          u16 h = f2bf(sigf(go)*tanhf_(c));
          int row = rowg0 + wv*16 + quad*4 + r;
          __hip_atomic_store((u16*)(dst + (size_t)row*256 + j*16 + n16), h,
                             __ATOMIC_RELAXED, __HIP_MEMORY_SCOPE_AGENT);
        }
      }
      __syncthreads();   // compiler drains vmcnt before s_barrier -> stores at LLC
      if (tid == 0)
        __hip_atomic_store(&flag1[b], t+1, __ATOMIC_RELEASE, __HIP_MEMORY_SCOPE_AGENT);
    }
    return;   // L0 workers exit; epilogue handled by L1 workers
  }

  // ======================= LAYER-1 WORKER =======================
  const int b  = blk - 64;
  const int bi = b >> 4, j = b & 15;
  const int rowg0 = bi * 64;
  int* f1p = flag1 + bi*16;
  int* f2g = flag2 + bi*16;

  for (int i = 0; i < 32; ++i) {
    int u = tid + i*256;               // 64 rows x 128 float4 ([Wih1|Whh1])
    int lr = u >> 7, c4 = u & 127;
    int wrow = (lr >> 4)*256 + j*16 + (lr & 15);
    float4 v = (c4 < 64) ? *(const float4*)(Wih1 + (size_t)wrow*256 + c4*4)
                         : *(const float4*)(Whh1 + (size_t)wrow*256 + (c4-64)*4);
    u16* d = smem + lr*SW1_STRIDE + c4*4;
    d[0]=f2bf(v.x); d[1]=f2bf(v.y); d[2]=f2bf(v.z); d[3]=f2bf(v.w);
  }
  float b1g[4];
  #pragma unroll
  for (int nt = 0; nt < 4; ++nt) {
    int wrow = nt*256 + j*16 + n16;
    b1g[nt] = bih1[wrow] + bhh1[wrow];
  }
  const u16* aP = smem + SA1_OFF + (wv*16 + n16)*SA1_STRIDE + quad*8;
  const u16* bP = smem + (n16)*SW1_STRIDE + quad*8;
  float c2r[4] = {0.f,0.f,0.f,0.f};

  for (int t = 0; t < NSTEPS; ++t) {
    if (wv == 0) {
      spinwait(f1p, l15, t+1);    // h1_t available (L0 runs ahead: slack)
      spinwait(f2g, l15, t);      // h2_{t-1} published by whole group
    }
    __syncthreads();
    { // stage h1_t -> sA[:,0:256] and h2_{t-1} -> sA[:,256:512]
      const bf16_t* s1 = ring1 + (size_t)(t&(RING_D-1))*SLOT_ELEMS + (size_t)rowg0*256;
      const bf16_t* s2 = ring2 + (size_t)((t+RING_D-1)&(RING_D-1))*SLOT_ELEMS
                       + (size_t)rowg0*256;
      #pragma unroll
      for (int i = 0; i < 16; ++i) {
        int u = tid + i*256;
        int row = u >> 6, c8 = u & 63;
        u64 v1 = __hip_atomic_load((const u64*)(s1 + row*256 + c8*4),
                                   __ATOMIC_RELAXED, __HIP_MEMORY_SCOPE_AGENT);
        u64 v2 = __hip_atomic_load((const u64*)(s2 + row*256 + c8*4),
                                   __ATOMIC_RELAXED, __HIP_MEMORY_SCOPE_AGENT);
        *(u64*)(smem + SA1_OFF + row*SA1_STRIDE + c8*4) = v1;
        *(u64*)(smem + SA1_OFF + row*SA1_STRIDE + 256 + c8*4) = v2;
      }
    }
    __syncthreads();
    f32x4 acc[4] = {{0,0,0,0},{0,0,0,0},{0,0,0,0},{0,0,0,0}};
    for (int kc = 0; kc < 16; ++kc) {            // K = 256(h1) + 256(h2)
      bf16x8 a = *(const bf16x8*)(aP + kc*32);
      #pragma unroll
      for (int nt = 0; nt < 4; ++nt) {
        bf16x8 bb = *(const bf16x8*)(bP + nt*16*SW1_STRIDE + kc*32);
        acc[nt] = __builtin_amdgcn_mfma_f32_16x16x32_bf16(a, bb, acc[nt], 0, 0, 0);
      }
    }
    {
      bf16_t* dst = ring2 + (size_t)(t&(RING_D-1))*SLOT_ELEMS;
      #pragma unroll
      for (int r = 0; r < 4; ++r) {
        float gi = acc[0][r] + b1g[0];
        float gf = acc[1][r] + b1g[1];
        float gg = acc[2][r] + b1g[2];
        float go = acc[3][r] + b1g[3];
        float c  = sigf(gf)*c2r[r] + sigf(gi)*tanhf_(gg);
        c2r[r] = c;
        u16 h = f2bf(sigf(go)*tanhf_(c));
        int row = rowg0 + wv*16 + quad*4 + r;
        __hip_atomic_store((u16*)(dst + (size_t)row*256 + j*16 + n16), h,
                           __ATOMIC_RELAXED, __HIP_MEMORY_SCOPE_AGENT);
      }
    }
    __syncthreads();
    if (tid == 0)
      __hip_atomic_store(&flag2[b], t+1, __ATOMIC_RELEASE, __HIP_MEMORY_SCOPE_AGENT);
  }

  // ============ epilogue: y = (h2_last @ W1^T + b1) @ W2^T + b2 ============
  // L1 block b handles batch rows b*4..b*4+3 (owning group grp = b>>4 = bi
  // only for its own rows? rows b*4.. belong to group (b*4)>>6 = b>>4).
  {
    const int grp = b >> 4;
    if (wv == 0) spinwait(flag2 + grp*16, l15, NSTEPS);
    __syncthreads();
    float* lastsh = (float*)smem;      // 4x256
    float* y1sh   = lastsh + 1024;     // 4x1280
    float* psum   = y1sh + 5120;       // 64
    {
      int row = tid >> 6, c8 = tid & 63;
      const bf16_t* src = ring2 + (size_t)((NSTEPS-1)&(RING_D-1))*SLOT_ELEMS
                        + (size_t)(b*4 + row)*256 + c8*4;
      u64 v = __hip_atomic_load((const u64*)src, __ATOMIC_RELAXED,
                                __HIP_MEMORY_SCOPE_AGENT);
      lastsh[row*256 + c8*4 + 0] = bf2f((u16)( v        & 0xffffu));
      lastsh[row*256 + c8*4 + 1] = bf2f((u16)((v >> 16) & 0xffffu));
      lastsh[row*256 + c8*4 + 2] = bf2f((u16)((v >> 32) & 0xffffu));
      lastsh[row*256 + c8*4 + 3] = bf2f((u16)((v >> 48) & 0xffffu));
    }
    __syncthreads();
    for (int i = 0; i < 5; ++i) {
      int m = tid + i*256;
      const float* wr = W1 + (size_t)m*256;
      float a0=0.f,a1=0.f,a2=0.f,a3=0.f;
      for (int k = 0; k < 256; ++k) {
        float w = wr[k];
        a0 += w*lastsh[k]; a1 += w*lastsh[256+k];
        a2 += w*lastsh[512+k]; a3 += w*lastsh[768+k];
      }
      float bb = b1[m];
      y1sh[m] = a0+bb; y1sh[1280+m] = a1+bb; y1sh[2560+m] = a2+bb; y1sh[3840+m] = a3+bb;
    }
    __syncthreads();
    if (tid < 64) {
      int row = tid >> 4, o = (tid >> 2) & 3, q = tid & 3;
      const float* w2r = W2 + (size_t)o*1280 + q*320;
      const float* yr  = y1sh + row*1280 + q*320;
      float s = 0.f;
      for (int m = 0; m < 320; ++m) s += w2r[m]*yr[m];
      psum[tid] = s;
    }
    __syncthreads();
    if (tid < 16) {
      int row = tid >> 2, o = tid & 3;
      out[(b*4 + row)*4 + o] = b2[o] + psum[tid*4+0] + psum[tid*4+1]
                                     + psum[tid*4+2] + psum[tid*4+3];
    }
  }
}

extern "C" void kernel_launch(void* const* d_in, const int* in_sizes, int n_in,
                              void* d_out, int out_size, void* d_ws, size_t ws_size,
                              hipStream_t stream) {
  (void)in_sizes; (void)n_in; (void)out_size; (void)ws_size;
  const float* x    = (const float*)d_in[0];
  const float* Wih0 = (const float*)d_in[1];
  const float* Whh0 = (const float*)d_in[2];
  const float* bih0 = (const float*)d_in[3];
  const float* bhh0 = (const float*)d_in[4];
  const float* Wih1 = (const float*)d_in[5];
  const float* Whh1 = (const float*)d_in[6];
  const float* bih1 = (const float*)d_in[7];
  const float* bhh1 = (const float*)d_in[8];
  const float* W1   = (const float*)d_in[9];
  const float* b1   = (const float*)d_in[10];
  const float* W2   = (const float*)d_in[11];
  const float* b2   = (const float*)d_in[12];
  float* out = (float*)d_out;
  char* ws   = (char*)d_ws;

  // rings + flags must be zeroed every call (ws is re-poisoned to 0xAA)
  hipLaunchKernelGGL(ws_init_kernel, dim3((WS_TOTAL/4 + 255)/256), dim3(256), 0, stream,
                     (u32*)ws, WS_TOTAL/4);

  hipFuncSetAttribute((const void*)lstm_persistent,
                      hipFuncAttributeMaxDynamicSharedMemorySize, SMEM_BYTES);

  void* args[] = { (void*)&x, (void*)&Wih0, (void*)&Whh0, (void*)&bih0, (void*)&bhh0,
                   (void*)&Wih1, (void*)&Whh1, (void*)&bih1, (void*)&bhh1,
                   (void*)&W1, (void*)&b1, (void*)&W2, (void*)&b2,
                   (void*)&out, (void*)&ws };
  // cooperative launch: all 128 blocks (1/CU, LDS-bound) co-resident
  hipLaunchCooperativeKernel((const void*)lstm_persistent, dim3(128), dim3(256),
                             args, SMEM_BYTES, stream);
}

// Round 5
// 3683.441 us; speedup vs baseline: 3.0287x; 1.2754x over previous
//
#include <hip/hip_runtime.h>
#include <stdint.h>

typedef unsigned short u16;
typedef unsigned int   u32;
typedef unsigned long long u64;
typedef __bf16 bf16_t;
typedef bf16_t bf16x8 __attribute__((ext_vector_type(8)));
typedef float  f32x4  __attribute__((ext_vector_type(4)));
typedef int    i32x4  __attribute__((ext_vector_type(4)));

#define NSTEPS 512
#define SPIN_LIM (1<<17)

// ---- workspace layout (bytes). EVERYTHING in ws is accessed ONLY via
// agent-scope atomics / sc1 ops -> LLC is the single coherence point,
// no XCD-L2 staleness surface (the R2/R3-proven path).
#define WS_RING1 0u          /* [4 grp][8 slot][64 row][256 col] u16 h1 ring */
#define WS_RING2 1048576u    /* [4 grp][4 slot][64 row][256 col] u16 h2 ring */
#define WS_F1    1572864u    /* [4][64] int per-wave flags, layer0 */
#define WS_F2    1573888u    /* [4][64] int per-wave flags, layer1 */
#define WS_TOTAL 1574912u

#define SMEM_BYTES (64*520*2)   /* 66560: L1 weight slice (L0 uses 64*328*2) */

__device__ __forceinline__ u16 f2bf(float f) {
  u32 u = __float_as_uint(f);
  return (u16)((u + 0x7fffu + ((u >> 16) & 1u)) >> 16);   // RNE
}
__device__ __forceinline__ float bf2f(u16 b) { return __uint_as_float(((u32)b) << 16); }
__device__ __forceinline__ float sigf(float x) { return 1.f / (1.f + __expf(-x)); }
__device__ __forceinline__ float tanhf_(float x) {
  float e = __expf(-2.f * fabsf(x));
  float t = (1.f - e) / (1.f + e);
  return x >= 0.f ? t : -t;
}

__device__ __forceinline__ void vmdrain() { asm volatile("s_waitcnt vmcnt(0)" ::: "memory"); }
__device__ __forceinline__ void st_u16_sc1(u16* p, u32 v) {
  asm volatile("global_store_short %0, %1, off sc1" :: "v"(p), "v"(v) : "memory");
}
__device__ __forceinline__ u64 ld_u64_sc1(const u64* p) {
  u64 v; asm volatile("global_load_dwordx2 %0, %1, off sc1\n\ts_waitcnt vmcnt(0)"
                      : "=v"(v) : "v"(p) : "memory"); return v;
}
// 8 x 16B A-fragment loads (64B apart = 32 elems) + single drain.
#define LD8_SC1()                                                          \
  asm volatile(                                                            \
    "global_load_dwordx4 %0, %8, off sc1\n\t"                              \
    "global_load_dwordx4 %1, %8, off offset:64 sc1\n\t"                    \
    "global_load_dwordx4 %2, %8, off offset:128 sc1\n\t"                   \
    "global_load_dwordx4 %3, %8, off offset:192 sc1\n\t"                   \
    "global_load_dwordx4 %4, %8, off offset:256 sc1\n\t"                   \
    "global_load_dwordx4 %5, %8, off offset:320 sc1\n\t"                   \
    "global_load_dwordx4 %6, %8, off offset:384 sc1\n\t"                   \
    "global_load_dwordx4 %7, %8, off offset:448 sc1\n\t"                   \
    "s_waitcnt vmcnt(0)"                                                   \
    : "=&v"(h[0]), "=&v"(h[1]), "=&v"(h[2]), "=&v"(h[3]),                  \
      "=&v"(h[4]), "=&v"(h[5]), "=&v"(h[6]), "=&v"(h[7])                   \
    : "v"(hp) : "memory")

// all-64-lane spin: lane i watches flag word i (agent scope -> LLC-coherent).
__device__ __forceinline__ void spin64(const int* f, int lane, int target) {
  if (target <= 0) return;
  int it = 0;
  for (;;) {
    int v = __hip_atomic_load(&f[lane], __ATOMIC_RELAXED, __HIP_MEMORY_SCOPE_AGENT);
    if (__all(v >= target)) return;
    if (++it > SPIN_LIM) return;      // bailout: wrong answer, never a hang
    __builtin_amdgcn_s_sleep(2);
  }
}

__global__ void ws_init_kernel(int* p, int n) {
  int i = blockIdx.x * blockDim.x + threadIdx.x;
  if (i < n)    // agent-scope stores -> zeros land at LLC
    __hip_atomic_store(&p[i], 0, __ATOMIC_RELAXED, __HIP_MEMORY_SCOPE_AGENT);
}

__device__ __forceinline__ bf16x8 pack_bf8(float4 a, float4 b) {
  union { u32 w[4]; bf16x8 v; } u_;
  u_.w[0] = (u32)f2bf(a.x) | ((u32)f2bf(a.y) << 16);
  u_.w[1] = (u32)f2bf(a.z) | ((u32)f2bf(a.w) << 16);
  u_.w[2] = (u32)f2bf(b.x) | ((u32)f2bf(b.y) << 16);
  u_.w[3] = (u32)f2bf(b.z) | ((u32)f2bf(b.w) << 16);
  return u_.v;
}

// Pipelined persistent 2-layer LSTM, 128 blocks x 256 threads.
// blk<64: layer-0 worker; blk>=64: layer-1 worker (+ epilogue).
// b=blk&63: bi=b>>4 (batch group, 64 rows), j=b&15 (16 h-cols slice).
// Wave wv = M-tile (16 rows); per-wave flag widx = j*4+wv (64/group/layer).
// MFMA 16x16x32_bf16: A[m=lane&15][k=quad*8+j] from ring via LD8;
// B[n=lane&15][k] from row-major padded LDS (R2/R3-proven layout);
// C/D col=lane&15, row=quad*4+reg -> acc[nt]=gate nt, lane-local pointwise,
// c-state in VGPRs for all 512 steps. Barrier-free main loops.
__global__ void __launch_bounds__(256)
lstm_persistent(const float* __restrict__ x,
                const float* __restrict__ Wih0, const float* __restrict__ Whh0,
                const float* __restrict__ bih0, const float* __restrict__ bhh0,
                const float* __restrict__ Wih1, const float* __restrict__ Whh1,
                const float* __restrict__ bih1, const float* __restrict__ bhh1,
                const float* __restrict__ W1, const float* __restrict__ b1,
                const float* __restrict__ W2, const float* __restrict__ b2,
                float* __restrict__ out, char* __restrict__ ws)
{
  extern __shared__ u16 smem[];
  const int tid  = threadIdx.x;
  const int lane = tid & 63;
  const int wv   = tid >> 6;
  const int n16  = lane & 15;
  const int quad = lane >> 4;
  const int blk  = blockIdx.x;
  const int layer = blk >> 6;
  const int b    = blk & 63;
  const int bi   = b >> 4, j = b & 15;
  const int j16  = j * 16;
  const int rowg0 = bi * 64;
  const int widx = j*4 + wv;
  const int arow = wv*16 + n16;          // my A-fragment row (group-local)

  u16* r1g = (u16*)(ws + WS_RING1) + (size_t)bi * 8 * 16384;
  u16* r2g = (u16*)(ws + WS_RING2) + (size_t)bi * 4 * 16384;
  int* f1g = (int*)(ws + WS_F1) + bi * 64;
  int* f2g = (int*)(ws + WS_F2) + bi * 64;

  float bg[4];
  #pragma unroll
  for (int nt = 0; nt < 4; ++nt) {
    int wrow = nt*256 + j16 + n16;
    bg[nt] = layer ? (bih1[wrow] + bhh1[wrow]) : (bih0[wrow] + bhh0[wrow]);
  }
  float cst[4] = {0.f,0.f,0.f,0.f};

  if (layer == 0) {
    // ---- stage W0 slice fp32->bf16 into LDS, row-major stride 328 ----
    for (int i = 0; i < 20; ++i) {
      int u = tid + i*256;               // 64 rows x 80 float4
      int lr = u / 80, c4 = u % 80;
      int wrow = (lr >> 4)*256 + j16 + (lr & 15);
      float4 v = (c4 < 16) ? *(const float4*)(Wih0 + (size_t)wrow*64 + c4*4)
                           : *(const float4*)(Whh0 + (size_t)wrow*256 + (c4-16)*4);
      u16* d = smem + lr*328 + c4*4;
      d[0]=f2bf(v.x); d[1]=f2bf(v.y); d[2]=f2bf(v.z); d[3]=f2bf(v.w);
    }
    __syncthreads();
    const u16* bP = smem + n16*328 + quad*8;

    for (int t = 0; t < NSTEPS; ++t) {
      // x_t prefetch (off critical path; in flight during spins)
      const float* xp = x + ((size_t)(rowg0 + arow)*NSTEPS + t)*64 + quad*8;
      float4 xa = *(const float4*)(xp);
      float4 xb = *(const float4*)(xp + 4);
      float4 xc = *(const float4*)(xp + 32);
      float4 xd = *(const float4*)(xp + 36);
      spin64(f1g, lane, t);       // h1_{t-1} published by all 64 waves
      spin64(f2g, lane, t - 7);   // ring1 depth-8 anti-dep (slack-covered)
      i32x4 h[8];
      { const u16* hp = r1g + (size_t)((t+7)&7)*16384 + arow*256 + quad*8;
        LD8_SC1(); }
      bf16x8 a0 = pack_bf8(xa, xb), a1 = pack_bf8(xc, xd);
      f32x4 acc[4] = {{0,0,0,0},{0,0,0,0},{0,0,0,0},{0,0,0,0}};
      #pragma unroll
      for (int nt = 0; nt < 4; ++nt)
        acc[nt] = __builtin_amdgcn_mfma_f32_16x16x32_bf16(
            a0, *(const bf16x8*)(bP + nt*16*328), acc[nt], 0,0,0);
      #pragma unroll
      for (int nt = 0; nt < 4; ++nt)
        acc[nt] = __builtin_amdgcn_mfma_f32_16x16x32_bf16(
            a1, *(const bf16x8*)(bP + nt*16*328 + 32), acc[nt], 0,0,0);
      #pragma unroll
      for (int kc = 2; kc < 10; ++kc) {
        bf16x8 a = __builtin_bit_cast(bf16x8, h[kc-2]);
        #pragma unroll
        for (int nt = 0; nt < 4; ++nt)
          acc[nt] = __builtin_amdgcn_mfma_f32_16x16x32_bf16(
              a, *(const bf16x8*)(bP + nt*16*328 + kc*32), acc[nt], 0,0,0);
      }
      u16* dst = r1g + (size_t)(t&7)*16384;
      #pragma unroll
      for (int r = 0; r < 4; ++r) {
        float gi = acc[0][r] + bg[0];
        float gf = acc[1][r] + bg[1];
        float gg = acc[2][r] + bg[2];
        float go = acc[3][r] + bg[3];
        float c  = sigf(gf)*cst[r] + sigf(gi)*tanhf_(gg);
        cst[r] = c;
        int rl = wv*16 + quad*4 + r;
        st_u16_sc1(dst + rl*256 + j16 + n16, f2bf(sigf(go)*tanhf_(c)));
      }
      vmdrain();
      if (lane == 0)
        __hip_atomic_store(&f1g[widx], t+1, __ATOMIC_RELAXED, __HIP_MEMORY_SCOPE_AGENT);
    }
    return;
  }

  // ======================= LAYER-1 WORKER =======================
  for (int i = 0; i < 32; ++i) {
    int u = tid + i*256;               // 64 rows x 128 float4 ([Wih1|Whh1])
    int lr = u >> 7, c4 = u & 127;
    int wrow = (lr >> 4)*256 + j16 + (lr & 15);
    float4 v = (c4 < 64) ? *(const float4*)(Wih1 + (size_t)wrow*256 + c4*4)
                         : *(const float4*)(Whh1 + (size_t)wrow*256 + (c4-64)*4);
    u16* d = smem + lr*520 + c4*4;
    d[0]=f2bf(v.x); d[1]=f2bf(v.y); d[2]=f2bf(v.z); d[3]=f2bf(v.w);
  }
  __syncthreads();
  const u16* bP = smem + n16*520 + quad*8;

  for (int t = 0; t < NSTEPS; ++t) {
    spin64(f1g, lane, t+1);       // h1_t ready (L0 leads; slack-covered)
    i32x4 h[8];
    { const u16* hp = r1g + (size_t)(t&7)*16384 + arow*256 + quad*8;
      LD8_SC1(); }
    f32x4 acc[4] = {{0,0,0,0},{0,0,0,0},{0,0,0,0},{0,0,0,0}};
    #pragma unroll
    for (int kc = 0; kc < 8; ++kc) {            // h1 half: off the h2 cycle
      bf16x8 a = __builtin_bit_cast(bf16x8, h[kc]);
      #pragma unroll
      for (int nt = 0; nt < 4; ++nt)
        acc[nt] = __builtin_amdgcn_mfma_f32_16x16x32_bf16(
            a, *(const bf16x8*)(bP + nt*16*520 + kc*32), acc[nt], 0,0,0);
    }
    spin64(f2g, lane, t);         // h2_{t-1} published by all 64 waves
    { const u16* hp = r2g + (size_t)((t+3)&3)*16384 + arow*256 + quad*8;
      LD8_SC1(); }
    #pragma unroll
    for (int kc = 0; kc < 8; ++kc) {
      bf16x8 a = __builtin_bit_cast(bf16x8, h[kc]);
      #pragma unroll
      for (int nt = 0; nt < 4; ++nt)
        acc[nt] = __builtin_amdgcn_mfma_f32_16x16x32_bf16(
            a, *(const bf16x8*)(bP + nt*16*520 + 256 + kc*32), acc[nt], 0,0,0);
    }
    u16* dst = r2g + (size_t)(t&3)*16384;
    #pragma unroll
    for (int r = 0; r < 4; ++r) {
      float gi = acc[0][r] + bg[0];
      float gf = acc[1][r] + bg[1];
      float gg = acc[2][r] + bg[2];
      float go = acc[3][r] + bg[3];
      float c  = sigf(gf)*cst[r] + sigf(gi)*tanhf_(gg);
      cst[r] = c;
      int rl = wv*16 + quad*4 + r;
      st_u16_sc1(dst + rl*256 + j16 + n16, f2bf(sigf(go)*tanhf_(c)));
    }
    vmdrain();
    if (lane == 0)
      __hip_atomic_store(&f2g[widx], t+1, __ATOMIC_RELAXED, __HIP_MEMORY_SCOPE_AGENT);
  }

  // ============ epilogue: y = (h2_T @ W1^T + b1) @ W2^T + b2 ============
  // L1 block b handles batch rows b*4..b*4+3 (within its own group bi).
  {
    spin64(f2g, lane, NSTEPS);
    __syncthreads();
    float* lastsh = (float*)smem;                 // 4x256
    float* y1sh   = lastsh + 1024;                // 4x1280
    float* psum   = y1sh + 5120;                  // 64
    {
      int row = tid >> 6, c8 = tid & 63;
      int lr = (b & 15)*4 + row;                  // group-local row
      u64 v = ld_u64_sc1((const u64*)(r2g + 3*16384 /*511&3*/ + lr*256 + c8*4));
      lastsh[row*256 + c8*4 + 0] = bf2f((u16)( v        & 0xffffu));
      lastsh[row*256 + c8*4 + 1] = bf2f((u16)((v >> 16) & 0xffffu));
      lastsh[row*256 + c8*4 + 2] = bf2f((u16)((v >> 32) & 0xffffu));
      lastsh[row*256 + c8*4 + 3] = bf2f((u16)((v >> 48) & 0xffffu));
    }
    __syncthreads();
    for (int i = 0; i < 5; ++i) {
      int m = tid + i*256;
      const float* wr = W1 + (size_t)m*256;
      float a0=0.f,a1=0.f,a2=0.f,a3=0.f;
      for (int k = 0; k < 256; ++k) {
        float w = wr[k];
        a0 += w*lastsh[k];     a1 += w*lastsh[256+k];
        a2 += w*lastsh[512+k]; a3 += w*lastsh[768+k];
      }
      float bb = b1[m];
      y1sh[m] = a0+bb; y1sh[1280+m] = a1+bb; y1sh[2560+m] = a2+bb; y1sh[3840+m] = a3+bb;
    }
    __syncthreads();
    if (tid < 64) {
      int row = tid >> 4, o = (tid >> 2) & 3, q = tid & 3;
      const float* w2r = W2 + (size_t)o*1280 + q*320;
      const float* yr  = y1sh + row*1280 + q*320;
      float s = 0.f;
      for (int m = 0; m < 320; ++m) s += w2r[m]*yr[m];
      psum[tid] = s;
    }
    __syncthreads();
    if (tid < 16) {
      int row = tid >> 2, o = tid & 3;
      out[(b*4 + row)*4 + o] = b2[o] + psum[tid*4+0] + psum[tid*4+1]
                                     + psum[tid*4+2] + psum[tid*4+3];
    }
  }
}

extern "C" void kernel_launch(void* const* d_in, const int* in_sizes, int n_in,
                              void* d_out, int out_size, void* d_ws, size_t ws_size,
                              hipStream_t stream) {
  (void)in_sizes; (void)n_in; (void)out_size; (void)ws_size;
  const float* x    = (const float*)d_in[0];
  const float* Wih0 = (const float*)d_in[1];
  const float* Whh0 = (const float*)d_in[2];
  const float* bih0 = (const float*)d_in[3];
  const float* bhh0 = (const float*)d_in[4];
  const float* Wih1 = (const float*)d_in[5];
  const float* Whh1 = (const float*)d_in[6];
  const float* bih1 = (const float*)d_in[7];
  const float* bhh1 = (const float*)d_in[8];
  const float* W1   = (const float*)d_in[9];
  const float* b1   = (const float*)d_in[10];
  const float* W2   = (const float*)d_in[11];
  const float* b2   = (const float*)d_in[12];
  float* out = (float*)d_out;
  char* ws   = (char*)d_ws;

  // zero rings + flags (ws re-poisoned to 0xAA before every timed launch)
  hipLaunchKernelGGL(ws_init_kernel, dim3((WS_TOTAL/4 + 255)/256), dim3(256),
                     0, stream, (int*)ws, (int)(WS_TOTAL/4));

  hipFuncSetAttribute((const void*)lstm_persistent,
                      hipFuncAttributeMaxDynamicSharedMemorySize, SMEM_BYTES);

  void* args[] = { (void*)&x, (void*)&Wih0, (void*)&Whh0, (void*)&bih0, (void*)&bhh0,
                   (void*)&Wih1, (void*)&Whh1, (void*)&bih1, (void*)&bhh1,
                   (void*)&W1, (void*)&b1, (void*)&W2, (void*)&b2,
                   (void*)&out, (void*)&ws };
  // cooperative launch: all 128 blocks co-resident (<= 256 CUs)
  hipLaunchCooperativeKernel((const void*)lstm_persistent, dim3(128), dim3(256),
                             args, SMEM_BYTES, stream);
}

// Round 6
// 2765.367 us; speedup vs baseline: 4.0342x; 1.3320x over previous
//
#include <hip/hip_runtime.h>
#include <stdint.h>

typedef unsigned short u16;
typedef unsigned int   u32;
typedef unsigned long long u64;
typedef __bf16 bf16_t;
typedef bf16_t bf16x8 __attribute__((ext_vector_type(8)));
typedef float  f32x4  __attribute__((ext_vector_type(4)));
typedef int    i32x4  __attribute__((ext_vector_type(4)));

#define NSTEPS 512
#define SPIN_LIM  (1<<17)
#define RETRY_LIM (1<<13)

// ---- workspace (bytes). All ws accesses are sc1/agent-scope -> LLC is the
// single coherence point (R2/R3/R5-proven path). Rings store u32 words:
// (step_tag << 16) | h_bf16  -> data is self-validating, no flags/fences.
#define WS_RING1 0u          /* [4 grp][4 slot][64 row][256 col] u32 h1 */
#define WS_RING2 1048576u    /* [4 grp][4 slot][64 row][256 col] u32 h2 */
#define WS_PROG  2097152u    /* [4 grp][64] int: L1 per-wave read progress */
#define WS_TOTAL 2098176u

#define SMEM_BYTES (64*520*2)   /* 66560: L1 weight slice (L0 uses 64*328*2) */

__device__ __forceinline__ u16 f2bf(float f) {
  u32 u = __float_as_uint(f);
  return (u16)((u + 0x7fffu + ((u >> 16) & 1u)) >> 16);   // RNE
}
__device__ __forceinline__ float bf2f(u16 b) { return __uint_as_float(((u32)b) << 16); }
__device__ __forceinline__ float sigf(float x) { return 1.f / (1.f + __expf(-x)); }
__device__ __forceinline__ float tanhf_(float x) {
  float e = __expf(-2.f * fabsf(x));
  float t = (1.f - e) / (1.f + e);
  return x >= 0.f ? t : -t;
}

__device__ __forceinline__ void st_u32_sc1(u32* p, u32 v) {
  asm volatile("global_store_dword %0, %1, off sc1" :: "v"(p), "v"(v) : "memory");
}
__device__ __forceinline__ u64 ld_u64_sc1(const u64* p) {
  u64 v; asm volatile("global_load_dwordx2 %0, %1, off sc1\n\ts_waitcnt vmcnt(0)"
                      : "=v"(v) : "v"(p) : "memory"); return v;
}

// 16 x 16B loads: lane's 64 tagged words of its A-row (8 chunks of 32 cols,
// lane covers cols quad*8..+7 of each chunk; row stride 1024B).
#define LD16(hp)                                                           \
  asm volatile(                                                            \
    "global_load_dwordx4 %0,  %16, off sc1\n\t"                            \
    "global_load_dwordx4 %1,  %16, off offset:16 sc1\n\t"                  \
    "global_load_dwordx4 %2,  %16, off offset:128 sc1\n\t"                 \
    "global_load_dwordx4 %3,  %16, off offset:144 sc1\n\t"                 \
    "global_load_dwordx4 %4,  %16, off offset:256 sc1\n\t"                 \
    "global_load_dwordx4 %5,  %16, off offset:272 sc1\n\t"                 \
    "global_load_dwordx4 %6,  %16, off offset:384 sc1\n\t"                 \
    "global_load_dwordx4 %7,  %16, off offset:400 sc1\n\t"                 \
    "global_load_dwordx4 %8,  %16, off offset:512 sc1\n\t"                 \
    "global_load_dwordx4 %9,  %16, off offset:528 sc1\n\t"                 \
    "global_load_dwordx4 %10, %16, off offset:640 sc1\n\t"                 \
    "global_load_dwordx4 %11, %16, off offset:656 sc1\n\t"                 \
    "global_load_dwordx4 %12, %16, off offset:768 sc1\n\t"                 \
    "global_load_dwordx4 %13, %16, off offset:784 sc1\n\t"                 \
    "global_load_dwordx4 %14, %16, off offset:896 sc1\n\t"                 \
    "global_load_dwordx4 %15, %16, off offset:912 sc1\n\t"                 \
    "s_waitcnt vmcnt(0)"                                                   \
    : "=&v"(h[0]), "=&v"(h[1]), "=&v"(h[2]),  "=&v"(h[3]),                 \
      "=&v"(h[4]), "=&v"(h[5]), "=&v"(h[6]),  "=&v"(h[7]),                 \
      "=&v"(h[8]), "=&v"(h[9]), "=&v"(h[10]), "=&v"(h[11]),                \
      "=&v"(h[12]),"=&v"(h[13]),"=&v"(h[14]), "=&v"(h[15])                 \
    : "v"(hp) : "memory")

// poll the data itself until every word's tag == want (self-validating sync)
#define TAGPOLL(hp, want) do {                                             \
    u32 tb = ((u32)(want)) << 16; int it_ = 0;                             \
    for (;;) {                                                             \
      LD16(hp);                                                            \
      u32 bad = 0;                                                         \
      _Pragma("unroll")                                                    \
      for (int q_ = 0; q_ < 16; ++q_)                                      \
        bad |= ((u32)h[q_][0] ^ tb) | ((u32)h[q_][1] ^ tb)                 \
             | ((u32)h[q_][2] ^ tb) | ((u32)h[q_][3] ^ tb);                \
      bad &= 0xffff0000u;                                                  \
      if (__all(bad == 0)) break;                                          \
      if (++it_ > RETRY_LIM) break;                                        \
      __builtin_amdgcn_s_sleep(1);                                         \
    }                                                                      \
  } while (0)

__device__ __forceinline__ bf16x8 frag_from(i32x4 lo, i32x4 hi) {
  union { u32 w[4]; bf16x8 v; } u_;
  u_.w[0] = ((u32)lo[0] & 0xffffu) | ((u32)lo[1] << 16);
  u_.w[1] = ((u32)lo[2] & 0xffffu) | ((u32)lo[3] << 16);
  u_.w[2] = ((u32)hi[0] & 0xffffu) | ((u32)hi[1] << 16);
  u_.w[3] = ((u32)hi[2] & 0xffffu) | ((u32)hi[3] << 16);
  return u_.v;
}
__device__ __forceinline__ bf16x8 pack_bf8(float4 a, float4 b) {
  union { u32 w[4]; bf16x8 v; } u_;
  u_.w[0] = (u32)f2bf(a.x) | ((u32)f2bf(a.y) << 16);
  u_.w[1] = (u32)f2bf(a.z) | ((u32)f2bf(a.w) << 16);
  u_.w[2] = (u32)f2bf(b.x) | ((u32)f2bf(b.y) << 16);
  u_.w[3] = (u32)f2bf(b.z) | ((u32)f2bf(b.w) << 16);
  return u_.v;
}

// lanes 0..63 watch prog words (L1 read-progress), used only for the rare
// ring1 anti-dependency (L1 lags -> L0 throttles to <=3 ahead).
__device__ __forceinline__ void spin64(const int* f, int lane, int target) {
  if (target <= 0) return;
  int it = 0;
  for (;;) {
    int v = __hip_atomic_load(&f[lane], __ATOMIC_RELAXED, __HIP_MEMORY_SCOPE_AGENT);
    if (__all(v >= target)) return;
    if (++it > SPIN_LIM) return;
    __builtin_amdgcn_s_sleep(2);
  }
}

__global__ void ws_init_kernel(int* p, int n) {
  int i = blockIdx.x * blockDim.x + threadIdx.x;
  if (i < n)    // agent-scope stores -> zeros at LLC (tag0 == h_{-1}=0)
    __hip_atomic_store(&p[i], 0, __ATOMIC_RELAXED, __HIP_MEMORY_SCOPE_AGENT);
}

// Pipelined persistent 2-layer LSTM, 128 blocks x 256 threads.
// blk<64: layer-0 worker; blk>=64: layer-1 worker (+ epilogue).
// b=blk&63: bi=b>>4 (batch group, 64 rows), j=b&15 (16-col slice).
// Wave wv = M-tile (16 rows). MFMA 16x16x32_bf16: A from tagged LLC ring
// (registers, no LDS staging), B from row-major padded LDS, C/D col=lane&15,
// row=quad*4+reg -> acc[nt]=gate nt, lane-local pointwise, c-state in VGPRs.
// Sync: data-embedded step tags; rings depth 4 (within-group skew <=1).
__global__ void __launch_bounds__(256)
lstm_persistent(const float* __restrict__ x,
                const float* __restrict__ Wih0, const float* __restrict__ Whh0,
                const float* __restrict__ bih0, const float* __restrict__ bhh0,
                const float* __restrict__ Wih1, const float* __restrict__ Whh1,
                const float* __restrict__ bih1, const float* __restrict__ bhh1,
                const float* __restrict__ W1, const float* __restrict__ b1,
                const float* __restrict__ W2, const float* __restrict__ b2,
                float* __restrict__ out, char* __restrict__ ws)
{
  extern __shared__ u16 smem[];
  const int tid  = threadIdx.x;
  const int lane = tid & 63;
  const int wv   = tid >> 6;
  const int n16  = lane & 15;
  const int quad = lane >> 4;
  const int blk  = blockIdx.x;
  const int layer = blk >> 6;
  const int b    = blk & 63;
  const int bi   = b >> 4, j = b & 15;
  const int j16  = j * 16;
  const int rowg0 = bi * 64;
  const int widx = j*4 + wv;
  const int arow = wv*16 + n16;          // my A-row (group-local)

  u32* r1g = (u32*)(ws + WS_RING1) + (size_t)bi * 4 * 16384;
  u32* r2g = (u32*)(ws + WS_RING2) + (size_t)bi * 4 * 16384;
  int* prg = (int*)(ws + WS_PROG) + bi * 64;

  float bg[4];
  #pragma unroll
  for (int nt = 0; nt < 4; ++nt) {
    int wrow = nt*256 + j16 + n16;
    bg[nt] = layer ? (bih1[wrow] + bhh1[wrow]) : (bih0[wrow] + bhh0[wrow]);
  }
  float cst[4] = {0.f,0.f,0.f,0.f};
  i32x4 h[16];

  if (layer == 0) {
    // ---- stage W0 slice fp32->bf16 into LDS, row-major stride 328 ----
    for (int i = 0; i < 20; ++i) {
      int u = tid + i*256;               // 64 rows x 80 float4
      int lr = u / 80, c4 = u % 80;
      int wrow = (lr >> 4)*256 + j16 + (lr & 15);
      float4 v = (c4 < 16) ? *(const float4*)(Wih0 + (size_t)wrow*64 + c4*4)
                           : *(const float4*)(Whh0 + (size_t)wrow*256 + (c4-16)*4);
      u16* d = smem + lr*328 + c4*4;
      d[0]=f2bf(v.x); d[1]=f2bf(v.y); d[2]=f2bf(v.z); d[3]=f2bf(v.w);
    }
    __syncthreads();
    const u16* bP = smem + n16*328 + quad*8;

    for (int t = 0; t < NSTEPS; ++t) {
      // x_t prefetch (in flight during poll)
      const float* xp = x + ((size_t)(rowg0 + arow)*NSTEPS + t)*64 + quad*8;
      float4 xa = *(const float4*)(xp);
      float4 xb = *(const float4*)(xp + 4);
      float4 xc = *(const float4*)(xp + 32);
      float4 xd = *(const float4*)(xp + 36);
      spin64(prg, lane, t - 3);     // ring1 anti-dep (L1 read-progress)
      { const char* hp = (const char*)(r1g + ((t+3)&3)*16384) + arow*1024 + quad*32;
        TAGPOLL(hp, t); }           // h1_{t-1}: tag t (t=0 -> zeros)
      bf16x8 a0 = pack_bf8(xa, xb), a1 = pack_bf8(xc, xd);
      f32x4 acc[4] = {{0,0,0,0},{0,0,0,0},{0,0,0,0},{0,0,0,0}};
      #pragma unroll
      for (int nt = 0; nt < 4; ++nt)
        acc[nt] = __builtin_amdgcn_mfma_f32_16x16x32_bf16(
            a0, *(const bf16x8*)(bP + nt*16*328), acc[nt], 0,0,0);
      #pragma unroll
      for (int nt = 0; nt < 4; ++nt)
        acc[nt] = __builtin_amdgcn_mfma_f32_16x16x32_bf16(
            a1, *(const bf16x8*)(bP + nt*16*328 + 32), acc[nt], 0,0,0);
      #pragma unroll
      for (int kc = 0; kc < 8; ++kc) {
        bf16x8 a = frag_from(h[2*kc], h[2*kc+1]);
        #pragma unroll
        for (int nt = 0; nt < 4; ++nt)
          acc[nt] = __builtin_amdgcn_mfma_f32_16x16x32_bf16(
              a, *(const bf16x8*)(bP + nt*16*328 + 64 + kc*32), acc[nt], 0,0,0);
      }
      u32 tag = ((u32)(t+1)) << 16;
      u32* dst = r1g + (t&3)*16384;
      #pragma unroll
      for (int r = 0; r < 4; ++r) {
        float gi = acc[0][r] + bg[0];
        float gf = acc[1][r] + bg[1];
        float gg = acc[2][r] + bg[2];
        float go = acc[3][r] + bg[3];
        float c  = sigf(gf)*cst[r] + sigf(gi)*tanhf_(gg);
        cst[r] = c;
        int rl = wv*16 + quad*4 + r;
        st_u32_sc1(dst + rl*256 + j16 + n16, tag | (u32)f2bf(sigf(go)*tanhf_(c)));
      }
      // no drain, no flag: consumers poll the tagged data itself
    }
    return;
  }

  // ======================= LAYER-1 WORKER =======================
  for (int i = 0; i < 32; ++i) {
    int u = tid + i*256;               // 64 rows x 128 float4 ([Wih1|Whh1])
    int lr = u >> 7, c4 = u & 127;
    int wrow = (lr >> 4)*256 + j16 + (lr & 15);
    float4 v = (c4 < 64) ? *(const float4*)(Wih1 + (size_t)wrow*256 + c4*4)
                         : *(const float4*)(Whh1 + (size_t)wrow*256 + (c4-64)*4);
    u16* d = smem + lr*520 + c4*4;
    d[0]=f2bf(v.x); d[1]=f2bf(v.y); d[2]=f2bf(v.z); d[3]=f2bf(v.w);
  }
  __syncthreads();
  const u16* bP = smem + n16*520 + quad*8;

  for (int t = 0; t < NSTEPS; ++t) {
    { const char* hp = (const char*)(r1g + (t&3)*16384) + arow*1024 + quad*32;
      TAGPOLL(hp, t+1); }           // h1_t (L0 leads; usually 1 poll)
    if (lane == 0)                  // read-progress for L0's anti-dep
      __hip_atomic_store(&prg[widx], t+1, __ATOMIC_RELAXED, __HIP_MEMORY_SCOPE_AGENT);
    f32x4 acc[4] = {{0,0,0,0},{0,0,0,0},{0,0,0,0},{0,0,0,0}};
    #pragma unroll
    for (int kc = 0; kc < 8; ++kc) {            // h1 half off the h2 cycle
      bf16x8 a = frag_from(h[2*kc], h[2*kc+1]);
      #pragma unroll
      for (int nt = 0; nt < 4; ++nt)
        acc[nt] = __builtin_amdgcn_mfma_f32_16x16x32_bf16(
            a, *(const bf16x8*)(bP + nt*16*520 + kc*32), acc[nt], 0,0,0);
    }
    { const char* hp = (const char*)(r2g + ((t+3)&3)*16384) + arow*1024 + quad*32;
      TAGPOLL(hp, t); }             // h2_{t-1}: tag t
    #pragma unroll
    for (int kc = 0; kc < 8; ++kc) {
      bf16x8 a = frag_from(h[2*kc], h[2*kc+1]);
      #pragma unroll
      for (int nt = 0; nt < 4; ++nt)
        acc[nt] = __builtin_amdgcn_mfma_f32_16x16x32_bf16(
            a, *(const bf16x8*)(bP + nt*16*520 + 256 + kc*32), acc[nt], 0,0,0);
    }
    u32 tag = ((u32)(t+1)) << 16;
    u32* dst = r2g + (t&3)*16384;
    #pragma unroll
    for (int r = 0; r < 4; ++r) {
      float gi = acc[0][r] + bg[0];
      float gf = acc[1][r] + bg[1];
      float gg = acc[2][r] + bg[2];
      float go = acc[3][r] + bg[3];
      float c  = sigf(gf)*cst[r] + sigf(gi)*tanhf_(gg);
      cst[r] = c;
      int rl = wv*16 + quad*4 + r;
      st_u32_sc1(dst + rl*256 + j16 + n16, tag | (u32)f2bf(sigf(go)*tanhf_(c)));
    }
  }

  // ============ epilogue: y = (h2_T @ W1^T + b1) @ W2^T + b2 ============
  // L1 block b handles batch rows b*4..b*4+3; h2_511 = tag 512 in slot 3.
  {
    float* lastsh = (float*)smem;                 // 4x256
    float* y1sh   = lastsh + 1024;                // 4x1280
    float* psum   = y1sh + 5120;                  // 64
    __syncthreads();
    {
      int row = tid >> 6, c = tid & 63;
      int lr = (b & 15)*4 + row;                  // group-local row
      #pragma unroll
      for (int rep = 0; rep < 2; ++rep) {
        int cc = c + rep*64;                      // u64 index: cols cc*2, cc*2+1
        const u64* p = (const u64*)((const char*)(r2g + 3*16384) + lr*1024 + cc*8);
        u64 v = 0; int it = 0;
        for (;;) {
          v = ld_u64_sc1(p);
          if (((v >> 16) & 0xffffull) == 512 && (v >> 48) == 512) break;
          if (++it > RETRY_LIM) break;
          __builtin_amdgcn_s_sleep(1);
        }
        lastsh[row*256 + cc*2 + 0] = bf2f((u16)(v & 0xffffu));
        lastsh[row*256 + cc*2 + 1] = bf2f((u16)((v >> 32) & 0xffffu));
      }
    }
    __syncthreads();
    for (int i = 0; i < 5; ++i) {
      int m = tid + i*256;
      const float* wr = W1 + (size_t)m*256;
      float a0=0.f,a1=0.f,a2=0.f,a3=0.f;
      for (int k = 0; k < 256; ++k) {
        float w = wr[k];
        a0 += w*lastsh[k];     a1 += w*lastsh[256+k];
        a2 += w*lastsh[512+k]; a3 += w*lastsh[768+k];
      }
      float bb = b1[m];
      y1sh[m] = a0+bb; y1sh[1280+m] = a1+bb; y1sh[2560+m] = a2+bb; y1sh[3840+m] = a3+bb;
    }
    __syncthreads();
    if (tid < 64) {
      int row = tid >> 4, o = (tid >> 2) & 3, q = tid & 3;
      const float* w2r = W2 + (size_t)o*1280 + q*320;
      const float* yr  = y1sh + row*1280 + q*320;
      float s = 0.f;
      for (int m = 0; m < 320; ++m) s += w2r[m]*yr[m];
      psum[tid] = s;
    }
    __syncthreads();
    if (tid < 16) {
      int row = tid >> 2, o = tid & 3;
      out[(b*4 + row)*4 + o] = b2[o] + psum[tid*4+0] + psum[tid*4+1]
                                     + psum[tid*4+2] + psum[tid*4+3];
    }
  }
}

extern "C" void kernel_launch(void* const* d_in, const int* in_sizes, int n_in,
                              void* d_out, int out_size, void* d_ws, size_t ws_size,
                              hipStream_t stream) {
  (void)in_sizes; (void)n_in; (void)out_size; (void)ws_size;
  const float* x    = (const float*)d_in[0];
  const float* Wih0 = (const float*)d_in[1];
  const float* Whh0 = (const float*)d_in[2];
  const float* bih0 = (const float*)d_in[3];
  const float* bhh0 = (const float*)d_in[4];
  const float* Wih1 = (const float*)d_in[5];
  const float* Whh1 = (const float*)d_in[6];
  const float* bih1 = (const float*)d_in[7];
  const float* bhh1 = (const float*)d_in[8];
  const float* W1   = (const float*)d_in[9];
  const float* b1   = (const float*)d_in[10];
  const float* W2   = (const float*)d_in[11];
  const float* b2   = (const float*)d_in[12];
  float* out = (float*)d_out;
  char* ws   = (char*)d_ws;

  // zero rings (tag0 == h_{-1}=0) + prog flags; ws re-poisoned every call
  hipLaunchKernelGGL(ws_init_kernel, dim3((WS_TOTAL/4 + 255)/256), dim3(256),
                     0, stream, (int*)ws, (int)(WS_TOTAL/4));

  hipFuncSetAttribute((const void*)lstm_persistent,
                      hipFuncAttributeMaxDynamicSharedMemorySize, SMEM_BYTES);

  void* args[] = { (void*)&x, (void*)&Wih0, (void*)&Whh0, (void*)&bih0, (void*)&bhh0,
                   (void*)&Wih1, (void*)&Whh1, (void*)&bih1, (void*)&bhh1,
                   (void*)&W1, (void*)&b1, (void*)&W2, (void*)&b2,
                   (void*)&out, (void*)&ws };
  // cooperative launch: all 128 blocks co-resident (<= 256 CUs)
  hipLaunchCooperativeKernel((const void*)lstm_persistent, dim3(128), dim3(256),
                             args, SMEM_BYTES, stream);
}